// Round 1
// baseline (2128.620 us; speedup 1.0000x reference)
//
#include <hip/hip_runtime.h>
#include <math.h>

#define D_MODEL 256
#define NHEAD   8
#define D_K     32
#define LSEQ    2048
#define BATCH   2
#define ROWS    (BATCH * LSEQ)   // 4096
#define D_FF    1024
#define UTOP    38

// ---------------------------------------------------------------------------
// Embedding + positional encoding: h[row,d] = (x[row,:]@emb_w[:,d] + b[d])*16 + PE(l,d)
// ---------------------------------------------------------------------------
__global__ __launch_bounds__(256) void k_embed(const float* __restrict__ x,
                                               const float* __restrict__ w,
                                               const float* __restrict__ b,
                                               float* __restrict__ h) {
    int row = blockIdx.x;           // b*L + l
    int l   = row & (LSEQ - 1);
    int d   = threadIdx.x;
    __shared__ float xs[32];
    if (d < 32) xs[d] = x[row * 32 + d];
    __syncthreads();
    float acc = 0.f;
#pragma unroll
    for (int i = 0; i < 32; ++i) acc += xs[i] * w[i * D_MODEL + d];
    acc = (acc + b[d]) * 16.0f;     // sqrt(256)
    int m = d >> 1;
    float div = expf(-(float)(2 * m) * (9.210340371976184f / 256.0f)); // ln(1e4)/256
    float ang = (float)l * div;
    float pe = (d & 1) ? cosf(ang) : sinf(ang);
    h[row * D_MODEL + d] = acc + pe;
}

// ---------------------------------------------------------------------------
// Generic fp32 tiled GEMM: C = A[M,K] @ W[K,N] + bias
// MODE 0: plain   MODE 1: relu   MODE 2: scatter to q/k/v layout [B,H,L,32]
// BM=BN=64, BK=16, 256 threads, 4x4 per thread.
// ---------------------------------------------------------------------------
template <int MODE>
__global__ __launch_bounds__(256) void k_gemm(const float* __restrict__ A,
                                              const float* __restrict__ W,
                                              const float* __restrict__ bias,
                                              float* __restrict__ C,
                                              int M, int N, int K) {
    __shared__ float As[16][68];
    __shared__ float Ws[16][68];
    const int t  = threadIdx.x;
    const int tx = t & 15, ty = t >> 4;
    const int m0 = blockIdx.x * 64, n0 = blockIdx.y * 64;
    float acc[4][4] = {};
    for (int k0 = 0; k0 < K; k0 += 16) {
        {
            int mr = t >> 2, kc = (t & 3) * 4;
            float4 av = *(const float4*)&A[(size_t)(m0 + mr) * K + k0 + kc];
            As[kc + 0][mr] = av.x; As[kc + 1][mr] = av.y;
            As[kc + 2][mr] = av.z; As[kc + 3][mr] = av.w;
            int kr = t >> 4, nc = (t & 15) * 4;
            *(float4*)&Ws[kr][nc] = *(const float4*)&W[(size_t)(k0 + kr) * N + n0 + nc];
        }
        __syncthreads();
#pragma unroll
        for (int k = 0; k < 16; ++k) {
            float4 a4 = *(const float4*)&As[k][ty * 4];
            float4 w4 = *(const float4*)&Ws[k][tx * 4];
            float av[4] = {a4.x, a4.y, a4.z, a4.w};
            float wv[4] = {w4.x, w4.y, w4.z, w4.w};
#pragma unroll
            for (int i = 0; i < 4; ++i)
#pragma unroll
                for (int j = 0; j < 4; ++j) acc[i][j] += av[i] * wv[j];
        }
        __syncthreads();
    }
#pragma unroll
    for (int i = 0; i < 4; ++i) {
        int row = m0 + ty * 4 + i;
#pragma unroll
        for (int j = 0; j < 4; ++j) {
            int col = n0 + tx * 4 + j;
            float v = acc[i][j] + bias[col];
            if (MODE == 1) v = fmaxf(v, 0.f);
            if (MODE == 2) {
                int bb = row >> 11, ll = row & (LSEQ - 1);
                int hh = col >> 5, dd = col & 31;
                C[(((size_t)(bb * NHEAD + hh) * LSEQ) + ll) * D_K + dd] = v;
            } else {
                C[(size_t)row * N + col] = v;
            }
        }
    }
}

// ---------------------------------------------------------------------------
// Fused ProbSparse attention: per wave, 2 query rows.
// scores -> exact top-38 threshold -> masked softmax -> ctx = attn @ V
// ---------------------------------------------------------------------------
__global__ __launch_bounds__(64) void k_attn(const float* __restrict__ Q,
                                             const float* __restrict__ Kt,
                                             const float* __restrict__ Vt,
                                             float* __restrict__ ctxb) {
    __shared__ float sc[2][LSEQ];
    __shared__ float lv[64];
    __shared__ int   li[64];
    __shared__ int   lcnt;

    const int lane = threadIdx.x;
    const int gr = blockIdx.x * 2;
    const int bh = gr >> 11;
    const int l0 = gr & (LSEQ - 1);
    const int b  = bh >> 3;
    const int hh = bh & 7;
    const float* Kb  = Kt + (size_t)bh * LSEQ * D_K;
    const float* Vb  = Vt + (size_t)bh * LSEQ * D_K;
    const float* q0p = Q + ((size_t)bh * LSEQ + l0) * D_K;

    float q0[32], q1[32];
#pragma unroll
    for (int d = 0; d < 32; ++d) { q0[d] = q0p[d]; q1[d] = q0p[32 + d]; }

    const float scale = 0.17677669529663687f; // 1/sqrt(32)

    float m0v = -INFINITY, m1v = -INFINITY;
    int   m0j = 0, m1j = 0;
    for (int j = 0; j < 32; ++j) {
        const float4* kp = (const float4*)(Kb + (size_t)(j * 64 + lane) * D_K);
        float a0 = 0.f, a1 = 0.f;
#pragma unroll
        for (int d4 = 0; d4 < 8; ++d4) {
            float4 kv = kp[d4];
            a0 += q0[d4*4+0]*kv.x + q0[d4*4+1]*kv.y + q0[d4*4+2]*kv.z + q0[d4*4+3]*kv.w;
            a1 += q1[d4*4+0]*kv.x + q1[d4*4+1]*kv.y + q1[d4*4+2]*kv.z + q1[d4*4+3]*kv.w;
        }
        a0 *= scale; a1 *= scale;
        sc[0][j * 64 + lane] = a0;
        sc[1][j * 64 + lane] = a1;
        if (a0 > m0v) { m0v = a0; m0j = j; }
        if (a1 > m1v) { m1v = a1; m1j = j; }
    }
    __syncthreads();

    for (int r = 0; r < 2; ++r) {
        float mv = r ? m1v : m0v;
        int   mj = r ? m1j : m0j;
        float* S = sc[r];
        float thr = 0.f, rowmax = 0.f;
        if (lane == 0) lcnt = UTOP;
        for (int it = 0; it < UTOP; ++it) {
            float v = mv;
            int   gi = mj * 64 + lane;
#pragma unroll
            for (int off = 32; off >= 1; off >>= 1) {
                float ov = __shfl_xor(v, off);
                int   oi = __shfl_xor(gi, off);
                if (ov > v || (ov == v && oi < gi)) { v = ov; gi = oi; }
            }
            if (it == 0) rowmax = v;
            if (it == UTOP - 1) thr = v;
            if (lane == 0) { lv[it] = v; li[it] = gi; }
            if ((gi & 63) == lane) {      // owner masks + rescans its 32 entries
                S[gi] = -INFINITY;
                mv = -INFINITY; mj = 0;
                for (int j = 0; j < 32; ++j) {
                    float s = S[j * 64 + lane];
                    if (s > mv) { mv = s; mj = j; }
                }
            }
        }
        __syncthreads();
        // tie sweep: remaining entries >= thr (reference keeps ALL >= thr)
        for (int j = 0; j < 32; ++j) {
            float s = S[j * 64 + lane];
            if (s >= thr) {
                int slot = atomicAdd(&lcnt, 1);
                if (slot < 64) { lv[slot] = s; li[slot] = j * 64 + lane; }
            }
        }
        __syncthreads();
        int cnt = lcnt; if (cnt > 64) cnt = 64;

        float psum = 0.f;
        for (int i = lane; i < cnt; i += 64) psum += expf(lv[i] - rowmax);
#pragma unroll
        for (int off = 32; off >= 1; off >>= 1) psum += __shfl_xor(psum, off);
        float inv = 1.0f / psum;

        int d = lane & 31, half = lane >> 5;
        float acc = 0.f;
        for (int i = half; i < cnt; i += 2) {
            float p = expf(lv[i] - rowmax);
            acc += p * Vb[(size_t)li[i] * D_K + d];
        }
        acc += __shfl_xor(acc, 32);
        if (lane < 32) {
            ctxb[((size_t)(b * LSEQ) + (l0 + r)) * D_MODEL + hh * D_K + d] = acc * inv;
        }
        __syncthreads();
    }
}

// ---------------------------------------------------------------------------
// Residual add + LayerNorm over 256, in place into h. One wave per row.
// ---------------------------------------------------------------------------
__global__ __launch_bounds__(64) void k_addln(float* __restrict__ h,
                                              const float* __restrict__ a,
                                              const float* __restrict__ g,
                                              const float* __restrict__ bb) {
    int row = blockIdx.x, lane = threadIdx.x;
    float4 hv = *(const float4*)&h[(size_t)row * D_MODEL + lane * 4];
    float4 av = *(const float4*)&a[(size_t)row * D_MODEL + lane * 4];
    float x0 = hv.x + av.x, x1 = hv.y + av.y, x2 = hv.z + av.z, x3 = hv.w + av.w;
    float s = x0 + x1 + x2 + x3;
#pragma unroll
    for (int off = 32; off >= 1; off >>= 1) s += __shfl_xor(s, off);
    float mean = s * (1.0f / 256.0f);
    float d0 = x0 - mean, d1 = x1 - mean, d2 = x2 - mean, d3 = x3 - mean;
    float vs = d0 * d0 + d1 * d1 + d2 * d2 + d3 * d3;
#pragma unroll
    for (int off = 32; off >= 1; off >>= 1) vs += __shfl_xor(vs, off);
    float inv = rsqrtf(vs * (1.0f / 256.0f) + 1e-5f);
    float4 gv = *(const float4*)&g[lane * 4];
    float4 bv = *(const float4*)&bb[lane * 4];
    float4 o;
    o.x = d0 * inv * gv.x + bv.x;
    o.y = d1 * inv * gv.y + bv.y;
    o.z = d2 * inv * gv.z + bv.z;
    o.w = d3 * inv * gv.w + bv.w;
    *(float4*)&h[(size_t)row * D_MODEL + lane * 4] = o;
}

// ---------------------------------------------------------------------------
// Decoder head: out[row, c] = h[row,:] @ dec_w[:, c] + dec_b[c]   (N=8)
// ---------------------------------------------------------------------------
__global__ __launch_bounds__(64) void k_dec(const float* __restrict__ h,
                                            const float* __restrict__ w,
                                            const float* __restrict__ b,
                                            float* __restrict__ out) {
    int row = blockIdx.x, lane = threadIdx.x;
    int c = lane & 7, part = lane >> 3;   // 8 parts x 32 dims
    float acc = 0.f;
    int d0 = part * 32;
#pragma unroll
    for (int dd = 0; dd < 32; ++dd) acc += h[(size_t)row * D_MODEL + d0 + dd] * w[(d0 + dd) * 8 + c];
    acc += __shfl_xor(acc, 8);
    acc += __shfl_xor(acc, 16);
    acc += __shfl_xor(acc, 32);
    if (lane < 8) out[(size_t)row * 8 + c] = acc + b[c];
}

// ---------------------------------------------------------------------------
extern "C" void kernel_launch(void* const* d_in, const int* in_sizes, int n_in,
                              void* d_out, int out_size, void* d_ws, size_t ws_size,
                              hipStream_t stream) {
    const float* x     = (const float*)d_in[0];
    const float* emb_w = (const float*)d_in[1];
    const float* emb_b = (const float*)d_in[2];
    const float* wq    = (const float*)d_in[3];
    const float* bq    = (const float*)d_in[4];
    const float* wk    = (const float*)d_in[5];
    const float* bk    = (const float*)d_in[6];
    const float* wv    = (const float*)d_in[7];
    const float* bv    = (const float*)d_in[8];
    const float* wo    = (const float*)d_in[9];
    const float* bo    = (const float*)d_in[10];
    const float* ln1_g = (const float*)d_in[11];
    const float* ln1_b = (const float*)d_in[12];
    const float* ln2_g = (const float*)d_in[13];
    const float* ln2_b = (const float*)d_in[14];
    const float* ff1_w = (const float*)d_in[15];
    const float* ff1_b = (const float*)d_in[16];
    const float* ff2_w = (const float*)d_in[17];
    const float* ff2_b = (const float*)d_in[18];
    const float* dec_w = (const float*)d_in[19];
    const float* dec_b = (const float*)d_in[20];

    float* ws   = (float*)d_ws;
    float* h    = ws;                      // 4096*256   = 1M floats
    float* qb   = h    + (1 << 20);        // 16*2048*32 = 1M
    float* kb   = qb   + (1 << 20);
    float* vb   = kb   + (1 << 20);
    float* ctxb = vb   + (1 << 20);        // 1M
    float* tmp  = ctxb + (1 << 20);        // 1M
    float* ffb  = tmp  + (1 << 20);        // 4096*1024 = 4M
    // total 10M floats = 40 MB

    k_embed<<<ROWS, 256, 0, stream>>>(x, emb_w, emb_b, h);

    for (int l = 0; l < 2; ++l) {
        const float* wql = wq + (size_t)l * 65536;  const float* bql = bq + l * 256;
        const float* wkl = wk + (size_t)l * 65536;  const float* bkl = bk + l * 256;
        const float* wvl = wv + (size_t)l * 65536;  const float* bvl = bv + l * 256;
        const float* wol = wo + (size_t)l * 65536;  const float* bol = bo + l * 256;

        dim3 g4(64, 4);
        k_gemm<2><<<g4, 256, 0, stream>>>(h, wql, bql, qb, ROWS, 256, 256);
        k_gemm<2><<<g4, 256, 0, stream>>>(h, wkl, bkl, kb, ROWS, 256, 256);
        k_gemm<2><<<g4, 256, 0, stream>>>(h, wvl, bvl, vb, ROWS, 256, 256);

        k_attn<<<(BATCH * NHEAD * LSEQ) / 2, 64, 0, stream>>>(qb, kb, vb, ctxb);

        k_gemm<0><<<g4, 256, 0, stream>>>(ctxb, wol, bol, tmp, ROWS, 256, 256);
        k_addln<<<ROWS, 64, 0, stream>>>(h, tmp, ln1_g + l * 256, ln1_b + l * 256);

        dim3 g16(64, 16);
        k_gemm<1><<<g16, 256, 0, stream>>>(h, ff1_w + (size_t)l * 262144, ff1_b + l * 1024,
                                           ffb, ROWS, D_FF, 256);
        k_gemm<0><<<g4, 256, 0, stream>>>(ffb, ff2_w + (size_t)l * 262144, ff2_b + l * 256,
                                          tmp, ROWS, 256, D_FF);
        k_addln<<<ROWS, 64, 0, stream>>>(h, tmp, ln2_g + l * 256, ln2_b + l * 256);
    }

    k_dec<<<ROWS, 64, 0, stream>>>(h, dec_w, dec_b, (float*)d_out);
}

// Round 2
// 1970.154 us; speedup vs baseline: 1.0804x; 1.0804x over previous
//
#include <hip/hip_runtime.h>
#include <math.h>

#define D_MODEL 256
#define NHEAD   8
#define D_K     32
#define LSEQ    2048
#define BATCH   2
#define ROWS    (BATCH * LSEQ)   // 4096
#define D_FF    1024
#define UTOP    38

// ---------------------------------------------------------------------------
// Embedding + positional encoding
// ---------------------------------------------------------------------------
__global__ __launch_bounds__(256) void k_embed(const float* __restrict__ x,
                                               const float* __restrict__ w,
                                               const float* __restrict__ b,
                                               float* __restrict__ h) {
    int row = blockIdx.x;           // b*L + l
    int l   = row & (LSEQ - 1);
    int d   = threadIdx.x;
    __shared__ float xs[32];
    if (d < 32) xs[d] = x[row * 32 + d];
    __syncthreads();
    float acc = 0.f;
#pragma unroll
    for (int i = 0; i < 32; ++i) acc += xs[i] * w[i * D_MODEL + d];
    acc = (acc + b[d]) * 16.0f;     // sqrt(256)
    int m = d >> 1;
    float div = expf(-(float)(2 * m) * (9.210340371976184f / 256.0f)); // ln(1e4)/256
    float ang = (float)l * div;
    float pe = (d & 1) ? cosf(ang) : sinf(ang);
    h[row * D_MODEL + d] = acc + pe;
}

// ---------------------------------------------------------------------------
// Generic fp32 tiled GEMM: C = A[M,K] @ W[K,N] + bias
// MODE 0: plain   MODE 1: relu   MODE 2: scatter to q/k/v layout [B,H,L,32]
// ---------------------------------------------------------------------------
template <int MODE>
__global__ __launch_bounds__(256) void k_gemm(const float* __restrict__ A,
                                              const float* __restrict__ W,
                                              const float* __restrict__ bias,
                                              float* __restrict__ C,
                                              int M, int N, int K) {
    __shared__ float As[16][68];
    __shared__ float Ws[16][68];
    const int t  = threadIdx.x;
    const int tx = t & 15, ty = t >> 4;
    const int m0 = blockIdx.x * 64, n0 = blockIdx.y * 64;
    float acc[4][4] = {};
    for (int k0 = 0; k0 < K; k0 += 16) {
        {
            int mr = t >> 2, kc = (t & 3) * 4;
            float4 av = *(const float4*)&A[(size_t)(m0 + mr) * K + k0 + kc];
            As[kc + 0][mr] = av.x; As[kc + 1][mr] = av.y;
            As[kc + 2][mr] = av.z; As[kc + 3][mr] = av.w;
            int kr = t >> 4, nc = (t & 15) * 4;
            *(float4*)&Ws[kr][nc] = *(const float4*)&W[(size_t)(k0 + kr) * N + n0 + nc];
        }
        __syncthreads();
#pragma unroll
        for (int k = 0; k < 16; ++k) {
            float4 a4 = *(const float4*)&As[k][ty * 4];
            float4 w4 = *(const float4*)&Ws[k][tx * 4];
            float av[4] = {a4.x, a4.y, a4.z, a4.w};
            float wv[4] = {w4.x, w4.y, w4.z, w4.w};
#pragma unroll
            for (int i = 0; i < 4; ++i)
#pragma unroll
                for (int j = 0; j < 4; ++j) acc[i][j] += av[i] * wv[j];
        }
        __syncthreads();
    }
#pragma unroll
    for (int i = 0; i < 4; ++i) {
        int row = m0 + ty * 4 + i;
#pragma unroll
        for (int j = 0; j < 4; ++j) {
            int col = n0 + tx * 4 + j;
            float v = acc[i][j] + bias[col];
            if (MODE == 1) v = fmaxf(v, 0.f);
            if (MODE == 2) {
                int bb = row >> 11, ll = row & (LSEQ - 1);
                int hh = col >> 5, dd = col & 31;
                C[(((size_t)(bb * NHEAD + hh) * LSEQ) + ll) * D_K + dd] = v;
            } else {
                C[(size_t)row * N + col] = v;
            }
        }
    }
}

// ---------------------------------------------------------------------------
// Fused ProbSparse attention, radix-select top-38.
// Block = 4 waves; each wave owns 2 query rows of the same (b,h).
// Scores kept as order-preserving uint32 keys in registers (32/row/lane).
// ---------------------------------------------------------------------------
__device__ __forceinline__ float key2f(unsigned int u) {
    unsigned int b = (u & 0x80000000u) ? (u ^ 0x80000000u) : ~u;
    return __uint_as_float(b);
}

__global__ __launch_bounds__(256, 3) void k_attn(const float* __restrict__ Q,
                                                 const float* __restrict__ Kt,
                                                 const float* __restrict__ Vt,
                                                 float* __restrict__ ctxb) {
    __shared__ int          hist[4][256];
    __shared__ float        lv[4][96];
    __shared__ int          li[4][96];
    __shared__ int          lcnt[4];
    __shared__ unsigned int sp[4];
    __shared__ int          sn[4];

    const int lane  = threadIdx.x & 63;
    const int wid   = threadIdx.x >> 6;
    const int bh    = blockIdx.x >> 8;        // grid = 16 bh * 256 chunks
    const int chunk = blockIdx.x & 255;
    const int l0    = chunk * 8 + wid * 2;
    const int b     = bh >> 3, hh = bh & 7;

    const float* Kb  = Kt + (size_t)bh * LSEQ * D_K;
    const float* Vb  = Vt + (size_t)bh * LSEQ * D_K;
    const float* q0p = Q + ((size_t)bh * LSEQ + l0) * D_K;

    float q0[32], q1[32];
#pragma unroll
    for (int d = 0; d < 32; ++d) { q0[d] = q0p[d]; q1[d] = q0p[32 + d]; }

    const float scale = 0.17677669529663687f; // 1/sqrt(32)
    unsigned int k0r[32], k1r[32];

#pragma unroll
    for (int j = 0; j < 32; ++j) {
        const float4* kp = (const float4*)(Kb + (size_t)(j * 64 + lane) * D_K);
        float a0 = 0.f, a1 = 0.f;
#pragma unroll
        for (int d4 = 0; d4 < 8; ++d4) {
            float4 kv = kp[d4];
            a0 += q0[d4*4+0]*kv.x + q0[d4*4+1]*kv.y + q0[d4*4+2]*kv.z + q0[d4*4+3]*kv.w;
            a1 += q1[d4*4+0]*kv.x + q1[d4*4+1]*kv.y + q1[d4*4+2]*kv.z + q1[d4*4+3]*kv.w;
        }
        unsigned int u0 = __float_as_uint(a0 * scale);
        unsigned int u1 = __float_as_uint(a1 * scale);
        k0r[j] = (u0 & 0x80000000u) ? ~u0 : (u0 | 0x80000000u);
        k1r[j] = (u1 & 0x80000000u) ? ~u1 : (u1 | 0x80000000u);
    }

    // process one row: exact radix-select of 38th-largest key, softmax, PV
    auto do_row = [&](const unsigned int (&kr)[32], int rr) {
        __syncthreads();   // protect lv/li/hist reuse across the two rows

        // row max (kept set always contains it)
        unsigned int mk = 0;
#pragma unroll
        for (int j = 0; j < 32; ++j) mk = max(mk, kr[j]);
#pragma unroll
        for (int off = 32; off >= 1; off >>= 1)
            mk = max(mk, (unsigned int)__shfl_xor((int)mk, off));
        const float rowmax = key2f(mk);

        unsigned int prefix = 0;
        int need = UTOP;
#pragma unroll
        for (int pass = 0; pass < 4; ++pass) {
            const int sh = 24 - pass * 8;
            const unsigned int maskHi = (pass == 0) ? 0u : (~0u << ((sh + 8) & 31));
            for (int i = lane; i < 256; i += 64) hist[wid][i] = 0;
            __syncthreads();
#pragma unroll
            for (int j = 0; j < 32; ++j) {
                unsigned int key = kr[j];
                if ((key & maskHi) == (prefix & maskHi))
                    atomicAdd(&hist[wid][(key >> sh) & 255], 1);
            }
            __syncthreads();
            // suffix scan over 256 bins (4 bins per lane, lane i owns 4i..4i+3)
            int b0 = hist[wid][lane * 4 + 0], b1 = hist[wid][lane * 4 + 1];
            int b2 = hist[wid][lane * 4 + 2], b3 = hist[wid][lane * 4 + 3];
            int c = b0 + b1 + b2 + b3;
            int t = c;
#pragma unroll
            for (int off = 1; off < 64; off <<= 1) {
                int o = __shfl_down(t, off);
                if (lane + off < 64) t += o;
            }
            int above = t - c;          // sum over lanes > lane (bins >= 4i+4)
            if (above < need && above + c >= need) {
                int cum = above, d, na;
                if (cum + b3 >= need)      { d = lane * 4 + 3; na = cum; }
                else { cum += b3;
                if (cum + b2 >= need)      { d = lane * 4 + 2; na = cum; }
                else { cum += b2;
                if (cum + b1 >= need)      { d = lane * 4 + 1; na = cum; }
                else { cum += b1;            d = lane * 4 + 0; na = cum; } } }
                sp[wid] = prefix | ((unsigned int)d << sh);
                sn[wid] = need - na;
            }
            __syncthreads();
            prefix = sp[wid];
            need   = sn[wid];
            __syncthreads();
        }
        const unsigned int thrkey = prefix;  // exact 38th-largest key

        // collect all entries >= thr (reference tie semantics)
        if (lane == 0) lcnt[wid] = 0;
        __syncthreads();
#pragma unroll
        for (int j = 0; j < 32; ++j) {
            unsigned int key = kr[j];
            if (key >= thrkey) {
                int slot = atomicAdd(&lcnt[wid], 1);
                if (slot < 96) { lv[wid][slot] = key2f(key); li[wid][slot] = j * 64 + lane; }
            }
        }
        __syncthreads();
        int cnt = lcnt[wid]; if (cnt > 96) cnt = 96;

        float psum = 0.f;
        for (int i = lane; i < cnt; i += 64) psum += expf(lv[wid][i] - rowmax);
#pragma unroll
        for (int off = 32; off >= 1; off >>= 1) psum += __shfl_xor(psum, off);
        float inv = 1.0f / psum;

        int d = lane & 31, half = lane >> 5;
        float acc = 0.f;
        for (int i = half; i < cnt; i += 2) {
            float p = expf(lv[wid][i] - rowmax);
            acc += p * Vb[(size_t)li[wid][i] * D_K + d];
        }
        acc += __shfl_xor(acc, 32);
        if (lane < 32)
            ctxb[((size_t)(b * LSEQ) + (l0 + rr)) * D_MODEL + hh * D_K + d] = acc * inv;
    };

    do_row(k0r, 0);
    do_row(k1r, 1);
}

// ---------------------------------------------------------------------------
// Residual add + LayerNorm over 256, in place into h. One wave per row.
// ---------------------------------------------------------------------------
__global__ __launch_bounds__(64) void k_addln(float* __restrict__ h,
                                              const float* __restrict__ a,
                                              const float* __restrict__ g,
                                              const float* __restrict__ bb) {
    int row = blockIdx.x, lane = threadIdx.x;
    float4 hv = *(const float4*)&h[(size_t)row * D_MODEL + lane * 4];
    float4 av = *(const float4*)&a[(size_t)row * D_MODEL + lane * 4];
    float x0 = hv.x + av.x, x1 = hv.y + av.y, x2 = hv.z + av.z, x3 = hv.w + av.w;
    float s = x0 + x1 + x2 + x3;
#pragma unroll
    for (int off = 32; off >= 1; off >>= 1) s += __shfl_xor(s, off);
    float mean = s * (1.0f / 256.0f);
    float d0 = x0 - mean, d1 = x1 - mean, d2 = x2 - mean, d3 = x3 - mean;
    float vs = d0 * d0 + d1 * d1 + d2 * d2 + d3 * d3;
#pragma unroll
    for (int off = 32; off >= 1; off >>= 1) vs += __shfl_xor(vs, off);
    float inv = rsqrtf(vs * (1.0f / 256.0f) + 1e-5f);
    float4 gv = *(const float4*)&g[lane * 4];
    float4 bv = *(const float4*)&bb[lane * 4];
    float4 o;
    o.x = d0 * inv * gv.x + bv.x;
    o.y = d1 * inv * gv.y + bv.y;
    o.z = d2 * inv * gv.z + bv.z;
    o.w = d3 * inv * gv.w + bv.w;
    *(float4*)&h[(size_t)row * D_MODEL + lane * 4] = o;
}

// ---------------------------------------------------------------------------
// Decoder head
// ---------------------------------------------------------------------------
__global__ __launch_bounds__(64) void k_dec(const float* __restrict__ h,
                                            const float* __restrict__ w,
                                            const float* __restrict__ b,
                                            float* __restrict__ out) {
    int row = blockIdx.x, lane = threadIdx.x;
    int c = lane & 7, part = lane >> 3;   // 8 parts x 32 dims
    float acc = 0.f;
    int d0 = part * 32;
#pragma unroll
    for (int dd = 0; dd < 32; ++dd) acc += h[(size_t)row * D_MODEL + d0 + dd] * w[(d0 + dd) * 8 + c];
    acc += __shfl_xor(acc, 8);
    acc += __shfl_xor(acc, 16);
    acc += __shfl_xor(acc, 32);
    if (lane < 8) out[(size_t)row * 8 + c] = acc + b[c];
}

// ---------------------------------------------------------------------------
extern "C" void kernel_launch(void* const* d_in, const int* in_sizes, int n_in,
                              void* d_out, int out_size, void* d_ws, size_t ws_size,
                              hipStream_t stream) {
    const float* x     = (const float*)d_in[0];
    const float* emb_w = (const float*)d_in[1];
    const float* emb_b = (const float*)d_in[2];
    const float* wq    = (const float*)d_in[3];
    const float* bq    = (const float*)d_in[4];
    const float* wk    = (const float*)d_in[5];
    const float* bk    = (const float*)d_in[6];
    const float* wv    = (const float*)d_in[7];
    const float* bv    = (const float*)d_in[8];
    const float* wo    = (const float*)d_in[9];
    const float* bo    = (const float*)d_in[10];
    const float* ln1_g = (const float*)d_in[11];
    const float* ln1_b = (const float*)d_in[12];
    const float* ln2_g = (const float*)d_in[13];
    const float* ln2_b = (const float*)d_in[14];
    const float* ff1_w = (const float*)d_in[15];
    const float* ff1_b = (const float*)d_in[16];
    const float* ff2_w = (const float*)d_in[17];
    const float* ff2_b = (const float*)d_in[18];
    const float* dec_w = (const float*)d_in[19];
    const float* dec_b = (const float*)d_in[20];

    float* ws   = (float*)d_ws;
    float* h    = ws;                      // 4096*256   = 1M floats
    float* qb   = h    + (1 << 20);
    float* kb   = qb   + (1 << 20);
    float* vb   = kb   + (1 << 20);
    float* ctxb = vb   + (1 << 20);
    float* tmp  = ctxb + (1 << 20);
    float* ffb  = tmp  + (1 << 20);        // 4096*1024 = 4M
    // total 10M floats = 40 MB

    k_embed<<<ROWS, 256, 0, stream>>>(x, emb_w, emb_b, h);

    for (int l = 0; l < 2; ++l) {
        const float* wql = wq + (size_t)l * 65536;  const float* bql = bq + l * 256;
        const float* wkl = wk + (size_t)l * 65536;  const float* bkl = bk + l * 256;
        const float* wvl = wv + (size_t)l * 65536;  const float* bvl = bv + l * 256;
        const float* wol = wo + (size_t)l * 65536;  const float* bol = bo + l * 256;

        dim3 g4(64, 4);
        k_gemm<2><<<g4, 256, 0, stream>>>(h, wql, bql, qb, ROWS, 256, 256);
        k_gemm<2><<<g4, 256, 0, stream>>>(h, wkl, bkl, kb, ROWS, 256, 256);
        k_gemm<2><<<g4, 256, 0, stream>>>(h, wvl, bvl, vb, ROWS, 256, 256);

        k_attn<<<NHEAD * BATCH * 256, 256, 0, stream>>>(qb, kb, vb, ctxb);

        k_gemm<0><<<g4, 256, 0, stream>>>(ctxb, wol, bol, tmp, ROWS, 256, 256);
        k_addln<<<ROWS, 64, 0, stream>>>(h, tmp, ln1_g + l * 256, ln1_b + l * 256);

        dim3 g16(64, 16);
        k_gemm<1><<<g16, 256, 0, stream>>>(h, ff1_w + (size_t)l * 262144, ff1_b + l * 1024,
                                           ffb, ROWS, D_FF, 256);
        k_gemm<0><<<g4, 256, 0, stream>>>(ffb, ff2_w + (size_t)l * 262144, ff2_b + l * 256,
                                          tmp, ROWS, 256, D_FF);
        k_addln<<<ROWS, 64, 0, stream>>>(h, tmp, ln2_g + l * 256, ln2_b + l * 256);
    }

    k_dec<<<ROWS, 64, 0, stream>>>(h, dec_w, dec_b, (float*)d_out);
}

// Round 3
// 1943.015 us; speedup vs baseline: 1.0955x; 1.0140x over previous
//
#include <hip/hip_runtime.h>
#include <math.h>

#define D_MODEL 256
#define NHEAD   8
#define D_K     32
#define LSEQ    2048
#define BATCH   2
#define ROWS    (BATCH * LSEQ)   // 4096
#define D_FF    1024
#define UTOP    38

// ---------------------------------------------------------------------------
// Embedding + positional encoding
// ---------------------------------------------------------------------------
__global__ __launch_bounds__(256) void k_embed(const float* __restrict__ x,
                                               const float* __restrict__ w,
                                               const float* __restrict__ b,
                                               float* __restrict__ h) {
    int row = blockIdx.x;           // b*L + l
    int l   = row & (LSEQ - 1);
    int d   = threadIdx.x;
    __shared__ float xs[32];
    if (d < 32) xs[d] = x[row * 32 + d];
    __syncthreads();
    float acc = 0.f;
#pragma unroll
    for (int i = 0; i < 32; ++i) acc += xs[i] * w[i * D_MODEL + d];
    acc = (acc + b[d]) * 16.0f;     // sqrt(256)
    int m = d >> 1;
    float div = expf(-(float)(2 * m) * (9.210340371976184f / 256.0f)); // ln(1e4)/256
    float ang = (float)l * div;
    float pe = (d & 1) ? cosf(ang) : sinf(ang);
    h[row * D_MODEL + d] = acc + pe;
}

// ---------------------------------------------------------------------------
// Generic fp32 tiled GEMM: C = A[M,K] @ W[K,N] + bias
// MODE 0: plain   MODE 1: relu   MODE 2: scatter to q/k/v layout [B,H,L,32]
// ---------------------------------------------------------------------------
template <int MODE>
__global__ __launch_bounds__(256) void k_gemm(const float* __restrict__ A,
                                              const float* __restrict__ W,
                                              const float* __restrict__ bias,
                                              float* __restrict__ C,
                                              int M, int N, int K) {
    __shared__ float As[16][68];
    __shared__ float Ws[16][68];
    const int t  = threadIdx.x;
    const int tx = t & 15, ty = t >> 4;
    const int m0 = blockIdx.x * 64, n0 = blockIdx.y * 64;
    float acc[4][4] = {};
    for (int k0 = 0; k0 < K; k0 += 16) {
        {
            int mr = t >> 2, kc = (t & 3) * 4;
            float4 av = *(const float4*)&A[(size_t)(m0 + mr) * K + k0 + kc];
            As[kc + 0][mr] = av.x; As[kc + 1][mr] = av.y;
            As[kc + 2][mr] = av.z; As[kc + 3][mr] = av.w;
            int kr = t >> 4, nc = (t & 15) * 4;
            *(float4*)&Ws[kr][nc] = *(const float4*)&W[(size_t)(k0 + kr) * N + n0 + nc];
        }
        __syncthreads();
#pragma unroll
        for (int k = 0; k < 16; ++k) {
            float4 a4 = *(const float4*)&As[k][ty * 4];
            float4 w4 = *(const float4*)&Ws[k][tx * 4];
            float av[4] = {a4.x, a4.y, a4.z, a4.w};
            float wv[4] = {w4.x, w4.y, w4.z, w4.w};
#pragma unroll
            for (int i = 0; i < 4; ++i)
#pragma unroll
                for (int j = 0; j < 4; ++j) acc[i][j] += av[i] * wv[j];
        }
        __syncthreads();
    }
#pragma unroll
    for (int i = 0; i < 4; ++i) {
        int row = m0 + ty * 4 + i;
#pragma unroll
        for (int j = 0; j < 4; ++j) {
            int col = n0 + tx * 4 + j;
            float v = acc[i][j] + bias[col];
            if (MODE == 1) v = fmaxf(v, 0.f);
            if (MODE == 2) {
                int bb = row >> 11, ll = row & (LSEQ - 1);
                int hh = col >> 5, dd = col & 31;
                C[(((size_t)(bb * NHEAD + hh) * LSEQ) + ll) * D_K + dd] = v;
            } else {
                C[(size_t)row * N + col] = v;
            }
        }
    }
}

// ---------------------------------------------------------------------------
// Fused ProbSparse attention.
// Block = 8 waves (512 thr); each wave owns 2 query rows of one (b,h).
// K staged in double-buffered LDS tiles [128][36] (padded, conflict-optimal).
// q rows live in SGPRs (readfirstlane), score keys in 64 VGPRs.
// Exact top-38 via wave-private 4x8-bit radix select (no barriers).
// ---------------------------------------------------------------------------
__device__ __forceinline__ unsigned int sortkey(float f) {
    unsigned int u = __float_as_uint(f);
    return (u & 0x80000000u) ? ~u : (u | 0x80000000u);
}
__device__ __forceinline__ float key2f(unsigned int u) {
    unsigned int b = (u & 0x80000000u) ? (u ^ 0x80000000u) : ~u;
    return __uint_as_float(b);
}

__global__ __launch_bounds__(512, 2) void k_attn(const float* __restrict__ Q,
                                                 const float* __restrict__ Kt,
                                                 const float* __restrict__ Vt,
                                                 float* __restrict__ ctxb) {
    __shared__ float Kl[2][128][36];     // 36.9 KB
    __shared__ int   hist[8][256];       // 8 KB
    __shared__ float lv[8][96];
    __shared__ int   li[8][96];
    __shared__ int   lcnt[8];

    const int tid   = threadIdx.x;
    const int lane  = tid & 63;
    const int wid   = tid >> 6;
    const int bh    = blockIdx.x >> 7;    // 16 bh x 128 chunks
    const int chunk = blockIdx.x & 127;
    const int row0  = chunk * 16 + wid * 2;
    const int b     = bh >> 3, hh = bh & 7;

    const float* Kb = Kt + (size_t)bh * LSEQ * D_K;
    const float* Vb = Vt + (size_t)bh * LSEQ * D_K;
    const float* qp = Q + ((size_t)bh * LSEQ + row0) * D_K;

    const float scale = 0.17677669529663687f; // 1/sqrt(32)
    // q rows are wave-uniform -> force into SGPRs, scale folded in
    float qa[32], qc[32];
#pragma unroll
    for (int d = 0; d < 32; ++d) {
        qa[d] = __uint_as_float(__builtin_amdgcn_readfirstlane(__float_as_uint(qp[d] * scale)));
        qc[d] = __uint_as_float(__builtin_amdgcn_readfirstlane(__float_as_uint(qp[32 + d] * scale)));
    }

    unsigned int k0[32], k1[32];

    // prologue: stage tile 0 (rows 0..127), 2 float4 per thread
    {
        int gid = tid * 2;
        float4 a  = *(const float4*)&Kb[(size_t)gid * 4];
        float4 b4 = *(const float4*)&Kb[(size_t)gid * 4 + 4];
        int r = gid >> 3, c = gid & 7;
        *(float4*)&Kl[0][r][c * 4]     = a;
        *(float4*)&Kl[0][r][c * 4 + 4] = b4;
    }
    __syncthreads();

    int cur = 0;
#pragma unroll
    for (int t = 0; t < 16; ++t) {
        float4 n0, n1;
        if (t < 15) {   // issue next-tile loads early (write-late)
            size_t base = (size_t)(t + 1) * 4096 + (size_t)tid * 8;
            n0 = *(const float4*)&Kb[base];
            n1 = *(const float4*)&Kb[base + 4];
        }
        float s00 = 0.f, s01 = 0.f, s10 = 0.f, s11 = 0.f;
#pragma unroll
        for (int c = 0; c < 8; ++c) {
            float4 kv0 = *(const float4*)&Kl[cur][lane][c * 4];
            float4 kv1 = *(const float4*)&Kl[cur][lane + 64][c * 4];
            s00 += qa[c*4+0]*kv0.x + qa[c*4+1]*kv0.y + qa[c*4+2]*kv0.z + qa[c*4+3]*kv0.w;
            s01 += qa[c*4+0]*kv1.x + qa[c*4+1]*kv1.y + qa[c*4+2]*kv1.z + qa[c*4+3]*kv1.w;
            s10 += qc[c*4+0]*kv0.x + qc[c*4+1]*kv0.y + qc[c*4+2]*kv0.z + qc[c*4+3]*kv0.w;
            s11 += qc[c*4+0]*kv1.x + qc[c*4+1]*kv1.y + qc[c*4+2]*kv1.z + qc[c*4+3]*kv1.w;
        }
        k0[2*t]   = sortkey(s00);
        k0[2*t+1] = sortkey(s01);
        k1[2*t]   = sortkey(s10);
        k1[2*t+1] = sortkey(s11);
        if (t < 15) {
            int gid = tid * 2;
            int r = gid >> 3, c = gid & 7;
            *(float4*)&Kl[cur ^ 1][r][c * 4]     = n0;
            *(float4*)&Kl[cur ^ 1][r][c * 4 + 4] = n1;
        }
        __syncthreads();
        cur ^= 1;
    }

    // per-wave select + softmax + PV; no cross-wave hazards below.
    auto do_row = [&](const unsigned int (&kr)[32], int rr) {
        unsigned int mk = 0;
#pragma unroll
        for (int j = 0; j < 32; ++j) mk = max(mk, kr[j]);
#pragma unroll
        for (int off = 32; off >= 1; off >>= 1) {
            unsigned int o = (unsigned int)__shfl_xor((int)mk, off);
            if (o > mk) mk = o;
        }
        const float rowmax = key2f(mk);

        unsigned int prefix = 0;
        int need = UTOP;
#pragma unroll
        for (int pass = 0; pass < 4; ++pass) {
            const int sh = 24 - pass * 8;
            *(int4*)&hist[wid][lane * 4] = make_int4(0, 0, 0, 0);
#pragma unroll
            for (int j = 0; j < 32; ++j) {
                unsigned int key = kr[j];
                bool m = (pass == 0) || ((key >> (sh + 8)) == (prefix >> (sh + 8)));
                if (m) atomicAdd(&hist[wid][(key >> sh) & 255], 1);
            }
            int4 hb = *(const int4*)&hist[wid][lane * 4];
            int c0 = hb.x, c1 = hb.y, c2 = hb.z, c3 = hb.w;
            int csum = c0 + c1 + c2 + c3;
            int suf = csum;
#pragma unroll
            for (int off = 1; off < 64; off <<= 1) {
                int o = __shfl_down(suf, off);
                if (lane + off < 64) suf += o;
            }
            int above = suf - csum;   // keys in strictly-higher bins
            bool found = (above < need) && (above + csum >= need);
            unsigned int cp = 0; int cn = 0;
            if (found) {
                int cum = above, d, na;
                if (cum + c3 >= need)      { d = 3; na = cum; }
                else { cum += c3;
                if (cum + c2 >= need)      { d = 2; na = cum; }
                else { cum += c2;
                if (cum + c1 >= need)      { d = 1; na = cum; }
                else { cum += c1;            d = 0; na = cum; } } }
                cp = prefix | ((unsigned int)(lane * 4 + d) << sh);
                cn = need - na;
            }
            unsigned long long bal = __ballot(found);
            int wl = (int)(__ffsll((unsigned long long)bal) - 1);
            prefix = (unsigned int)__shfl((int)cp, wl);
            need   = __shfl(cn, wl);
        }
        const unsigned int thrkey = prefix;   // exact 38th-largest key

        if (lane == 0) lcnt[wid] = 0;
#pragma unroll
        for (int j = 0; j < 32; ++j) {
            if (kr[j] >= thrkey) {
                int slot = atomicAdd(&lcnt[wid], 1);
                if (slot < 96) {
                    lv[wid][slot] = key2f(kr[j]);
                    li[wid][slot] = (j >> 1) * 128 + (j & 1) * 64 + lane;
                }
            }
        }
        int cnt = lcnt[wid]; if (cnt > 96) cnt = 96;

        float psum = 0.f;
        for (int i = lane; i < cnt; i += 64) psum += expf(lv[wid][i] - rowmax);
#pragma unroll
        for (int off = 32; off >= 1; off >>= 1) psum += __shfl_xor(psum, off);
        float inv = 1.0f / psum;

        int d = lane & 31, half = lane >> 5;
        float acc = 0.f;
        for (int i = half; i < cnt; i += 2)
            acc += expf(lv[wid][i] - rowmax) * Vb[(size_t)li[wid][i] * D_K + d];
        acc += __shfl_xor(acc, 32);
        if (lane < 32)
            ctxb[((size_t)(b * LSEQ) + (row0 + rr)) * D_MODEL + hh * D_K + d] = acc * inv;
    };

    do_row(k0, 0);
    do_row(k1, 1);
}

// ---------------------------------------------------------------------------
// Residual add + LayerNorm over 256, in place into h. One wave per row.
// ---------------------------------------------------------------------------
__global__ __launch_bounds__(64) void k_addln(float* __restrict__ h,
                                              const float* __restrict__ a,
                                              const float* __restrict__ g,
                                              const float* __restrict__ bb) {
    int row = blockIdx.x, lane = threadIdx.x;
    float4 hv = *(const float4*)&h[(size_t)row * D_MODEL + lane * 4];
    float4 av = *(const float4*)&a[(size_t)row * D_MODEL + lane * 4];
    float x0 = hv.x + av.x, x1 = hv.y + av.y, x2 = hv.z + av.z, x3 = hv.w + av.w;
    float s = x0 + x1 + x2 + x3;
#pragma unroll
    for (int off = 32; off >= 1; off >>= 1) s += __shfl_xor(s, off);
    float mean = s * (1.0f / 256.0f);
    float d0 = x0 - mean, d1 = x1 - mean, d2 = x2 - mean, d3 = x3 - mean;
    float vs = d0 * d0 + d1 * d1 + d2 * d2 + d3 * d3;
#pragma unroll
    for (int off = 32; off >= 1; off >>= 1) vs += __shfl_xor(vs, off);
    float inv = rsqrtf(vs * (1.0f / 256.0f) + 1e-5f);
    float4 gv = *(const float4*)&g[lane * 4];
    float4 bv = *(const float4*)&bb[lane * 4];
    float4 o;
    o.x = d0 * inv * gv.x + bv.x;
    o.y = d1 * inv * gv.y + bv.y;
    o.z = d2 * inv * gv.z + bv.z;
    o.w = d3 * inv * gv.w + bv.w;
    *(float4*)&h[(size_t)row * D_MODEL + lane * 4] = o;
}

// ---------------------------------------------------------------------------
// Decoder head
// ---------------------------------------------------------------------------
__global__ __launch_bounds__(64) void k_dec(const float* __restrict__ h,
                                            const float* __restrict__ w,
                                            const float* __restrict__ b,
                                            float* __restrict__ out) {
    int row = blockIdx.x, lane = threadIdx.x;
    int c = lane & 7, part = lane >> 3;   // 8 parts x 32 dims
    float acc = 0.f;
    int d0 = part * 32;
#pragma unroll
    for (int dd = 0; dd < 32; ++dd) acc += h[(size_t)row * D_MODEL + d0 + dd] * w[(d0 + dd) * 8 + c];
    acc += __shfl_xor(acc, 8);
    acc += __shfl_xor(acc, 16);
    acc += __shfl_xor(acc, 32);
    if (lane < 8) out[(size_t)row * 8 + c] = acc + b[c];
}

// ---------------------------------------------------------------------------
extern "C" void kernel_launch(void* const* d_in, const int* in_sizes, int n_in,
                              void* d_out, int out_size, void* d_ws, size_t ws_size,
                              hipStream_t stream) {
    const float* x     = (const float*)d_in[0];
    const float* emb_w = (const float*)d_in[1];
    const float* emb_b = (const float*)d_in[2];
    const float* wq    = (const float*)d_in[3];
    const float* bq    = (const float*)d_in[4];
    const float* wk    = (const float*)d_in[5];
    const float* bk    = (const float*)d_in[6];
    const float* wv    = (const float*)d_in[7];
    const float* bv    = (const float*)d_in[8];
    const float* wo    = (const float*)d_in[9];
    const float* bo    = (const float*)d_in[10];
    const float* ln1_g = (const float*)d_in[11];
    const float* ln1_b = (const float*)d_in[12];
    const float* ln2_g = (const float*)d_in[13];
    const float* ln2_b = (const float*)d_in[14];
    const float* ff1_w = (const float*)d_in[15];
    const float* ff1_b = (const float*)d_in[16];
    const float* ff2_w = (const float*)d_in[17];
    const float* ff2_b = (const float*)d_in[18];
    const float* dec_w = (const float*)d_in[19];
    const float* dec_b = (const float*)d_in[20];

    float* ws   = (float*)d_ws;
    float* h    = ws;                      // 4096*256   = 1M floats
    float* qb   = h    + (1 << 20);
    float* kb   = qb   + (1 << 20);
    float* vb   = kb   + (1 << 20);
    float* ctxb = vb   + (1 << 20);
    float* tmp  = ctxb + (1 << 20);
    float* ffb  = tmp  + (1 << 20);        // 4096*1024 = 4M

    k_embed<<<ROWS, 256, 0, stream>>>(x, emb_w, emb_b, h);

    for (int l = 0; l < 2; ++l) {
        const float* wql = wq + (size_t)l * 65536;  const float* bql = bq + l * 256;
        const float* wkl = wk + (size_t)l * 65536;  const float* bkl = bk + l * 256;
        const float* wvl = wv + (size_t)l * 65536;  const float* bvl = bv + l * 256;
        const float* wol = wo + (size_t)l * 65536;  const float* bol = bo + l * 256;

        dim3 g4(64, 4);
        k_gemm<2><<<g4, 256, 0, stream>>>(h, wql, bql, qb, ROWS, 256, 256);
        k_gemm<2><<<g4, 256, 0, stream>>>(h, wkl, bkl, kb, ROWS, 256, 256);
        k_gemm<2><<<g4, 256, 0, stream>>>(h, wvl, bvl, vb, ROWS, 256, 256);

        k_attn<<<NHEAD * BATCH * 128, 512, 0, stream>>>(qb, kb, vb, ctxb);

        k_gemm<0><<<g4, 256, 0, stream>>>(ctxb, wol, bol, tmp, ROWS, 256, 256);
        k_addln<<<ROWS, 64, 0, stream>>>(h, tmp, ln1_g + l * 256, ln1_b + l * 256);

        dim3 g16(64, 16);
        k_gemm<1><<<g16, 256, 0, stream>>>(h, ff1_w + (size_t)l * 262144, ff1_b + l * 1024,
                                           ffb, ROWS, D_FF, 256);
        k_gemm<0><<<g4, 256, 0, stream>>>(ffb, ff2_w + (size_t)l * 262144, ff2_b + l * 256,
                                          tmp, ROWS, 256, D_FF);
        k_addln<<<ROWS, 64, 0, stream>>>(h, tmp, ln2_g + l * 256, ln2_b + l * 256);
    }

    k_dec<<<ROWS, 64, 0, stream>>>(h, dec_w, dec_b, (float*)d_out);
}